// Round 1
// baseline (274.277 us; speedup 1.0000x reference)
//
#include <hip/hip_runtime.h>
#include <math.h>

#define NB 4
#define NL 512
#define SD 256
#define PD 128
#define NH 8
#define HD 32

// ws offsets (floats)
#define OFF_S    0
#define OFF_Q    (524288)
#define OFF_K    (524288*2)
#define OFF_V    (524288*3)
#define OFF_G    (524288*4)
#define OFF_PRE  (524288*5)
#define OFF_BIAS (524288*6)
#define OFF_WP   (OFF_BIAS + 8388608)
#define OFF_CGB  (OFF_WP + 1024)

// ---------------- K1a: LN(seq) + weight precompute ----------------
__global__ __launch_bounds__(256) void k_prep(
    const float* __restrict__ seq, const float* __restrict__ lsg, const float* __restrict__ lsb,
    const float* __restrict__ lpg, const float* __restrict__ lpb, const float* __restrict__ Wb,
    float* __restrict__ sws, float* __restrict__ Wp, float* __restrict__ Cgb) {
  int t = threadIdx.x;
  if (blockIdx.x == 512) {
    if (t < 128) {
      float g = lpg[t];
#pragma unroll
      for (int n = 0; n < 8; ++n) Wp[t*8+n] = g * Wb[t*8+n];
    } else if (t < 136) {
      int n = t - 128;
      float cg = 0.f, cb = 0.f;
      for (int p = 0; p < 128; ++p) {
        float wb = Wb[p*8+n];
        cg = fmaf(lpg[p], wb, cg);
        cb = fmaf(lpb[p], wb, cb);
      }
      Cgb[n] = cg; Cgb[8+n] = cb;
    }
    return;
  }
  int wv = t >> 6, lane = t & 63;
  int row = blockIdx.x*4 + wv;
  const float* x = seq + row*SD;
  float4 v = *(const float4*)(x + 4*lane);
  float sum = v.x + v.y + v.z + v.w;
  float sq  = v.x*v.x + v.y*v.y + v.z*v.z + v.w*v.w;
#pragma unroll
  for (int mm = 1; mm < 64; mm <<= 1) {
    sum += __shfl_xor(sum, mm);
    sq  += __shfl_xor(sq,  mm);
  }
  float mu = sum * (1.f/256.f);
  float var = sq * (1.f/256.f) - mu*mu;
  float rstd = rsqrtf(var + 1e-5f);
  float4 g  = *(const float4*)(lsg + 4*lane);
  float4 bb = *(const float4*)(lsb + 4*lane);
  float4 o;
  o.x = (v.x - mu)*rstd*g.x + bb.x;
  o.y = (v.y - mu)*rstd*g.y + bb.y;
  o.z = (v.z - mu)*rstd*g.z + bb.z;
  o.w = (v.w - mu)*rstd*g.w + bb.w;
  *(float4*)(sws + row*SD + 4*lane) = o;
}

// ---------------- K1b: QKVG projections ----------------
__global__ __launch_bounds__(256) void k_qkvg(
    const float* __restrict__ sws, const float* __restrict__ Wq, const float* __restrict__ Wk,
    const float* __restrict__ Wv, const float* __restrict__ Wg, const float* __restrict__ bg,
    float qscale,
    float* __restrict__ Qw, float* __restrict__ Kw, float* __restrict__ Vw, float* __restrict__ Gw) {
  __shared__ __align__(16) float As[256*36];
  int t = threadIdx.x;
  int m0 = blockIdx.x * 32;
  int y = blockIdx.y;
  {
    int r = t >> 3, c0 = t & 7;
    const float* srow = sws + (m0 + r)*256;
#pragma unroll
    for (int qq = 0; qq < 8; ++qq) {
      int c4 = c0 + 8*qq;
      float4 v = *(const float4*)(srow + 4*c4);
      float* dp = As + 4*c4*36 + r;
      dp[0] = v.x; dp[36] = v.y; dp[72] = v.z; dp[108] = v.w;
    }
  }
  __syncthreads();
  const float* Wm = (y < 2) ? Wq : (y < 4) ? Wk : (y < 6) ? Wv : Wg;
  int cb = (y & 1) * 128;
  int rg = t >> 5, cg = t & 31;
  const float* bp = Wm + cb + 4*cg;
  const float* ap = As + 4*rg;
  float4 a0 = {0,0,0,0}, a1 = {0,0,0,0}, a2 = {0,0,0,0}, a3 = {0,0,0,0};
#pragma unroll 4
  for (int p = 0; p < 256; ++p) {
    float4 a  = *(const float4*)(ap + p*36);
    float4 bv = *(const float4*)(bp + p*256);
    a0.x = fmaf(a.x, bv.x, a0.x); a0.y = fmaf(a.x, bv.y, a0.y);
    a0.z = fmaf(a.x, bv.z, a0.z); a0.w = fmaf(a.x, bv.w, a0.w);
    a1.x = fmaf(a.y, bv.x, a1.x); a1.y = fmaf(a.y, bv.y, a1.y);
    a1.z = fmaf(a.y, bv.z, a1.z); a1.w = fmaf(a.y, bv.w, a1.w);
    a2.x = fmaf(a.z, bv.x, a2.x); a2.y = fmaf(a.z, bv.y, a2.y);
    a2.z = fmaf(a.z, bv.z, a2.z); a2.w = fmaf(a.z, bv.w, a2.w);
    a3.x = fmaf(a.w, bv.x, a3.x); a3.y = fmaf(a.w, bv.y, a3.y);
    a3.z = fmaf(a.w, bv.z, a3.z); a3.w = fmaf(a.w, bv.w, a3.w);
  }
  int mat = y >> 1;
  int col = cb + 4*cg;
  float* outp = (mat == 0) ? Qw : (mat == 1) ? Kw : (mat == 2) ? Vw : Gw;
  if (mat == 0) {
    a0.x*=qscale; a0.y*=qscale; a0.z*=qscale; a0.w*=qscale;
    a1.x*=qscale; a1.y*=qscale; a1.z*=qscale; a1.w*=qscale;
    a2.x*=qscale; a2.y*=qscale; a2.z*=qscale; a2.w*=qscale;
    a3.x*=qscale; a3.y*=qscale; a3.z*=qscale; a3.w*=qscale;
  }
  if (mat == 3) {
    float4 g4 = *(const float4*)(bg + col);
    a0.x = 1.f/(1.f+__expf(-(a0.x+g4.x))); a0.y = 1.f/(1.f+__expf(-(a0.y+g4.y)));
    a0.z = 1.f/(1.f+__expf(-(a0.z+g4.z))); a0.w = 1.f/(1.f+__expf(-(a0.w+g4.w)));
    a1.x = 1.f/(1.f+__expf(-(a1.x+g4.x))); a1.y = 1.f/(1.f+__expf(-(a1.y+g4.y)));
    a1.z = 1.f/(1.f+__expf(-(a1.z+g4.z))); a1.w = 1.f/(1.f+__expf(-(a1.w+g4.w)));
    a2.x = 1.f/(1.f+__expf(-(a2.x+g4.x))); a2.y = 1.f/(1.f+__expf(-(a2.y+g4.y)));
    a2.z = 1.f/(1.f+__expf(-(a2.z+g4.z))); a2.w = 1.f/(1.f+__expf(-(a2.w+g4.w)));
    a3.x = 1.f/(1.f+__expf(-(a3.x+g4.x))); a3.y = 1.f/(1.f+__expf(-(a3.y+g4.y)));
    a3.z = 1.f/(1.f+__expf(-(a3.z+g4.z))); a3.w = 1.f/(1.f+__expf(-(a3.w+g4.w)));
  }
  int orow = m0 + 4*rg;
  *(float4*)(outp + (size_t)(orow+0)*256 + col) = a0;
  *(float4*)(outp + (size_t)(orow+1)*256 + col) = a1;
  *(float4*)(outp + (size_t)(orow+2)*256 + col) = a2;
  *(float4*)(outp + (size_t)(orow+3)*256 + col) = a3;
}

// ---------------- K2: pair LN + bias projection (HBM-bound) ----------------
__global__ __launch_bounds__(128) void k_bias(
    const float* __restrict__ pair, const float* __restrict__ Wp, const float* __restrict__ Cgb,
    float* __restrict__ biasw) {
  __shared__ float sm[128*129];
  int t = threadIdx.x;
  int b = blockIdx.x >> 9, i = blockIdx.x & 511;
  const float* prow = pair + (size_t)(b*512 + i) * (512*128);
  float cg[8], cb[8];
#pragma unroll
  for (int n = 0; n < 8; ++n) { cg[n] = Cgb[n]; cb[n] = Cgb[8+n]; }
  float* bp0 = biasw + (size_t)(b*8)*262144 + (size_t)i*512;
  for (int c = 0; c < 4; ++c) {
    int j0 = c*128;
    const float* src = prow + (size_t)j0*128;
#pragma unroll 4
    for (int it = 0; it < 32; ++it) {
      int idx = it*128 + t;
      int row = idx >> 5, c4 = idx & 31;
      float4 v = *(const float4*)(src + row*128 + 4*c4);
      float* d = sm + row*129 + 4*c4;
      d[0]=v.x; d[1]=v.y; d[2]=v.z; d[3]=v.w;
    }
    __syncthreads();
    float sum=0.f, sq=0.f;
    float dd[8] = {0,0,0,0,0,0,0,0};
    const float* my = sm + t*129;
#pragma unroll 4
    for (int k = 0; k < 128; ++k) {
      float x = my[k];
      const float* wk = Wp + k*8;   // k is wave-uniform -> s_load broadcast
      sum += x; sq = fmaf(x, x, sq);
#pragma unroll
      for (int n = 0; n < 8; ++n) dd[n] = fmaf(x, wk[n], dd[n]);
    }
    float mu = sum * (1.f/128.f);
    float var = sq * (1.f/128.f) - mu*mu;
    float rstd = rsqrtf(var + 1e-5f);
    int j = j0 + t;
#pragma unroll
    for (int n = 0; n < 8; ++n)
      bp0[(size_t)n*262144 + j] = fmaf(rstd, dd[n] - mu*cg[n], cb[n]);
    __syncthreads();
  }
}

// ---------------- K3: fused attention (online softmax) ----------------
__global__ __launch_bounds__(256) void k_attn(
    const float* __restrict__ Qw, const float* __restrict__ Kw, const float* __restrict__ Vw,
    const float* __restrict__ Gw, const float* __restrict__ biasw, float* __restrict__ prew) {
  __shared__ __align__(16) float sm[18496];
  float* Kl = sm;
  float* Vl = sm + 9248;
  int t = threadIdx.x;
  int b = blockIdx.x >> 6;
  int i0 = (blockIdx.x & 63) << 3;
  int lane = t & 63, w = t >> 6;
  int i = lane >> 3, n = lane & 7;
  int qrow = b*512 + i0 + i;
  float4 q[8];
  const float* qp = Qw + (size_t)qrow*256 + n*32;
#pragma unroll
  for (int x = 0; x < 8; ++x) q[x] = *(const float4*)(qp + 4*x);
  const float* brow = biasw + (size_t)((b*8 + n)*512 + i0 + i)*512 + 8*w;
  float4 acc[8];
#pragma unroll
  for (int x = 0; x < 8; ++x) acc[x] = make_float4(0.f,0.f,0.f,0.f);
  float m = -1e30f, l = 0.f;
  int sr = t >> 3, sc = t & 7;
  const float* kbase = Kw + (size_t)(b*512 + sr)*256 + 4*sc;
  const float* vbase = Vw + (size_t)(b*512 + sr)*256 + 4*sc;
  float* kd = Kl + 36*sr + 4*sc;
  float* vd = Vl + 36*sr + 4*sc;
  for (int tt = 0; tt < 16; ++tt) {
    int j0 = tt*32;
    const float* ks = kbase + (size_t)j0*256;
    const float* vs = vbase + (size_t)j0*256;
#pragma unroll
    for (int s = 0; s < 8; ++s)
      *(float4*)(kd + 1156*s) = *(const float4*)(ks + 32*s);
#pragma unroll
    for (int s = 0; s < 8; ++s)
      *(float4*)(vd + 1156*s) = *(const float4*)(vs + 32*s);
    __syncthreads();
    float4 b0 = *(const float4*)(brow + j0);
    float4 b1 = *(const float4*)(brow + j0 + 4);
    float bb[8] = {b0.x,b0.y,b0.z,b0.w,b1.x,b1.y,b1.z,b1.w};
    float lg[8];
    const float* kp0 = Kl + 1156*n + 36*(8*w);
#pragma unroll
    for (int jj = 0; jj < 8; ++jj) {
      const float* kp = kp0 + 36*jj;
      float d0 = 0.f;
#pragma unroll
      for (int x = 0; x < 8; ++x) {
        float4 kk = *(const float4*)(kp + 4*x);
        d0 = fmaf(q[x].x, kk.x, d0);
        d0 = fmaf(q[x].y, kk.y, d0);
        d0 = fmaf(q[x].z, kk.z, d0);
        d0 = fmaf(q[x].w, kk.w, d0);
      }
      lg[jj] = d0 + bb[jj];
    }
    float tm = lg[0];
#pragma unroll
    for (int jj = 1; jj < 8; ++jj) tm = fmaxf(tm, lg[jj]);
    float nm = fmaxf(m, tm);
    float scl = __expf(m - nm);
    l *= scl;
#pragma unroll
    for (int x = 0; x < 8; ++x) {
      acc[x].x *= scl; acc[x].y *= scl; acc[x].z *= scl; acc[x].w *= scl;
    }
    m = nm;
    const float* vp0 = Vl + 1156*n + 36*(8*w);
#pragma unroll
    for (int jj = 0; jj < 8; ++jj) {
      float p = __expf(lg[jj] - m);
      l += p;
      const float* vp = vp0 + 36*jj;
#pragma unroll
      for (int x = 0; x < 8; ++x) {
        float4 vv = *(const float4*)(vp + 4*x);
        acc[x].x = fmaf(p, vv.x, acc[x].x);
        acc[x].y = fmaf(p, vv.y, acc[x].y);
        acc[x].z = fmaf(p, vv.z, acc[x].z);
        acc[x].w = fmaf(p, vv.w, acc[x].w);
      }
    }
    __syncthreads();
  }
  // cross-wave merge
  float* me = sm + t*37;
  me[0] = m; me[1] = l;
#pragma unroll
  for (int x = 0; x < 8; ++x) {
    me[2+4*x+0] = acc[x].x; me[2+4*x+1] = acc[x].y;
    me[2+4*x+2] = acc[x].z; me[2+4*x+3] = acc[x].w;
  }
  __syncthreads();
  if (w == 0) {
    float mw[4], lw[4];
    float M = -1e30f;
#pragma unroll
    for (int v4 = 0; v4 < 4; ++v4) {
      const float* pe = sm + (v4*64 + lane)*37;
      mw[v4] = pe[0]; lw[v4] = pe[1];
      M = fmaxf(M, mw[v4]);
    }
    float Lsum = 0.f, ew[4];
#pragma unroll
    for (int v4 = 0; v4 < 4; ++v4) { ew[v4] = __expf(mw[v4] - M); Lsum = fmaf(lw[v4], ew[v4], Lsum); }
    float inv = 1.f / Lsum;
    float o[32];
#pragma unroll
    for (int h = 0; h < 32; ++h) o[h] = 0.f;
#pragma unroll
    for (int v4 = 0; v4 < 4; ++v4) {
      const float* pe = sm + (v4*64 + lane)*37 + 2;
      float e = ew[v4];
#pragma unroll
      for (int h = 0; h < 32; ++h) o[h] = fmaf(pe[h], e, o[h]);
    }
    const float* gp = Gw + (size_t)qrow*256 + n*32;
    float* op = prew + (size_t)qrow*256 + n*32;
#pragma unroll
    for (int x = 0; x < 8; ++x) {
      float4 g4 = *(const float4*)(gp + 4*x);
      float4 r;
      r.x = o[4*x+0]*inv*g4.x;
      r.y = o[4*x+1]*inv*g4.y;
      r.z = o[4*x+2]*inv*g4.z;
      r.w = o[4*x+3]*inv*g4.w;
      *(float4*)(op + 4*x) = r;
    }
  }
}

// ---------------- K4: output projection ----------------
__global__ __launch_bounds__(256) void k_out(
    const float* __restrict__ prew, const float* __restrict__ Wo, const float* __restrict__ bo,
    float* __restrict__ out) {
  __shared__ __align__(16) float As[256*36];
  int t = threadIdx.x;
  int m0 = blockIdx.x * 32;
  int y = blockIdx.y;
  {
    int r = t >> 3, c0 = t & 7;
    const float* srow = prew + (size_t)(m0 + r)*256;
#pragma unroll
    for (int qq = 0; qq < 8; ++qq) {
      int c4 = c0 + 8*qq;
      float4 v = *(const float4*)(srow + 4*c4);
      float* dp = As + 4*c4*36 + r;
      dp[0] = v.x; dp[36] = v.y; dp[72] = v.z; dp[108] = v.w;
    }
  }
  __syncthreads();
  int cb = y*128;
  int rg = t >> 5, cg = t & 31;
  int col = cb + 4*cg;
  const float* bp = Wo + col;
  const float* ap = As + 4*rg;
  float4 a0 = {0,0,0,0}, a1 = {0,0,0,0}, a2 = {0,0,0,0}, a3 = {0,0,0,0};
#pragma unroll 4
  for (int p = 0; p < 256; ++p) {
    float4 a  = *(const float4*)(ap + p*36);
    float4 bv = *(const float4*)(bp + p*256);
    a0.x = fmaf(a.x, bv.x, a0.x); a0.y = fmaf(a.x, bv.y, a0.y);
    a0.z = fmaf(a.x, bv.z, a0.z); a0.w = fmaf(a.x, bv.w, a0.w);
    a1.x = fmaf(a.y, bv.x, a1.x); a1.y = fmaf(a.y, bv.y, a1.y);
    a1.z = fmaf(a.y, bv.z, a1.z); a1.w = fmaf(a.y, bv.w, a1.w);
    a2.x = fmaf(a.z, bv.x, a2.x); a2.y = fmaf(a.z, bv.y, a2.y);
    a2.z = fmaf(a.z, bv.z, a2.z); a2.w = fmaf(a.z, bv.w, a2.w);
    a3.x = fmaf(a.w, bv.x, a3.x); a3.y = fmaf(a.w, bv.y, a3.y);
    a3.z = fmaf(a.w, bv.z, a3.z); a3.w = fmaf(a.w, bv.w, a3.w);
  }
  float4 b4 = *(const float4*)(bo + col);
  a0.x += b4.x; a0.y += b4.y; a0.z += b4.z; a0.w += b4.w;
  a1.x += b4.x; a1.y += b4.y; a1.z += b4.z; a1.w += b4.w;
  a2.x += b4.x; a2.y += b4.y; a2.z += b4.z; a2.w += b4.w;
  a3.x += b4.x; a3.y += b4.y; a3.z += b4.z; a3.w += b4.w;
  int orow = m0 + 4*rg;
  *(float4*)(out + (size_t)(orow+0)*256 + col) = a0;
  *(float4*)(out + (size_t)(orow+1)*256 + col) = a1;
  *(float4*)(out + (size_t)(orow+2)*256 + col) = a2;
  *(float4*)(out + (size_t)(orow+3)*256 + col) = a3;
}

extern "C" void kernel_launch(void* const* d_in, const int* in_sizes, int n_in,
                              void* d_out, int out_size, void* d_ws, size_t ws_size,
                              hipStream_t stream) {
  const float* seq  = (const float*)d_in[0];
  const float* pair = (const float*)d_in[1];
  const float* lsg  = (const float*)d_in[2];
  const float* lsb  = (const float*)d_in[3];
  const float* lpg  = (const float*)d_in[4];
  const float* lpb  = (const float*)d_in[5];
  const float* Wb   = (const float*)d_in[6];
  const float* Wq   = (const float*)d_in[7];
  const float* Wk   = (const float*)d_in[8];
  const float* Wv   = (const float*)d_in[9];
  const float* Wg   = (const float*)d_in[10];
  const float* bg   = (const float*)d_in[11];
  const float* Wo   = (const float*)d_in[12];
  const float* bo   = (const float*)d_in[13];
  float* ws   = (float*)d_ws;
  float* sws  = ws + OFF_S;
  float* Qw   = ws + OFF_Q;
  float* Kw   = ws + OFF_K;
  float* Vw   = ws + OFF_V;
  float* Gw   = ws + OFF_G;
  float* prew = ws + OFF_PRE;
  float* biasw= ws + OFF_BIAS;
  float* Wp   = ws + OFF_WP;
  float* Cgb  = ws + OFF_CGB;
  float* out  = (float*)d_out;

  hipLaunchKernelGGL(k_prep, dim3(513), dim3(256), 0, stream,
                     seq, lsg, lsb, lpg, lpb, Wb, sws, Wp, Cgb);
  hipLaunchKernelGGL(k_qkvg, dim3(64, 8), dim3(256), 0, stream,
                     sws, Wq, Wk, Wv, Wg, bg, 0.17677669529663687f, Qw, Kw, Vw, Gw);
  hipLaunchKernelGGL(k_bias, dim3(2048), dim3(128), 0, stream,
                     pair, Wp, Cgb, biasw);
  hipLaunchKernelGGL(k_attn, dim3(256), dim3(256), 0, stream,
                     Qw, Kw, Vw, Gw, biasw, prew);
  hipLaunchKernelGGL(k_out, dim3(64, 2), dim3(256), 0, stream,
                     prew, Wo, bo, out);
}

// Round 2
// 251.113 us; speedup vs baseline: 1.0922x; 1.0922x over previous
//
#include <hip/hip_runtime.h>
#include <math.h>

#define NB 4
#define NL 512
#define SD 256
#define PD 128
#define NH 8
#define HD 32

// ws offsets (floats)
#define OFF_Q    0
#define OFF_K    (524288)
#define OFF_V    (524288*2)
#define OFF_G    (524288*3)
#define OFF_PRE  (524288*4)
#define OFF_BIAS (524288*5)

// select a[f] from 8 register-resident floats without scratch (constant indices)
#define SEL8(a, f, out) do { \
  float _s0 = ((f)&1) ? a[1] : a[0]; \
  float _s1 = ((f)&1) ? a[3] : a[2]; \
  float _s2 = ((f)&1) ? a[5] : a[4]; \
  float _s3 = ((f)&1) ? a[7] : a[6]; \
  float _t0 = ((f)&2) ? _s1 : _s0; \
  float _t1 = ((f)&2) ? _s3 : _s2; \
  out = ((f)&4) ? _t1 : _t0; \
} while(0)

// ---------------- K1: mega (qkvg with fused LN  +  pair LN/bias) ----------------
__global__ __launch_bounds__(256) void k_mega(
    const float* __restrict__ seq, const float* __restrict__ lsg, const float* __restrict__ lsb,
    const float* __restrict__ lpg, const float* __restrict__ lpb, const float* __restrict__ Wb,
    const float* __restrict__ Wq, const float* __restrict__ Wk, const float* __restrict__ Wv,
    const float* __restrict__ Wg, const float* __restrict__ bg, const float* __restrict__ pair,
    float* __restrict__ Qw, float* __restrict__ Kw, float* __restrict__ Vw, float* __restrict__ Gw,
    float* __restrict__ biasw) {
  __shared__ __align__(16) float As[256*36];
  int t = threadIdx.x;
  int blk = blockIdx.x;

  if (blk < 512) {
    // ---- qkvg path: LN(seq rows) + GEMM 32x(256)x128-slice ----
    int m0 = (blk >> 3) * 32;
    int y = blk & 7;
    {
      int r = t >> 3, c0 = t & 7;
      const float* srow = seq + (size_t)(m0 + r) * 256;
      float4 v[8];
      float s = 0.f, sq = 0.f;
#pragma unroll
      for (int qq = 0; qq < 8; ++qq) {
        v[qq] = *(const float4*)(srow + 4*(c0 + 8*qq));
        s += v[qq].x + v[qq].y + v[qq].z + v[qq].w;
        sq = fmaf(v[qq].x, v[qq].x, sq); sq = fmaf(v[qq].y, v[qq].y, sq);
        sq = fmaf(v[qq].z, v[qq].z, sq); sq = fmaf(v[qq].w, v[qq].w, sq);
      }
#pragma unroll
      for (int mm = 1; mm < 8; mm <<= 1) { s += __shfl_xor(s, mm); sq += __shfl_xor(sq, mm); }
      float mu = s * (1.f/256.f);
      float var = sq * (1.f/256.f) - mu*mu;
      float rstd = rsqrtf(var + 1e-5f);
#pragma unroll
      for (int qq = 0; qq < 8; ++qq) {
        int c4 = c0 + 8*qq;
        float4 g  = *(const float4*)(lsg + 4*c4);
        float4 bb = *(const float4*)(lsb + 4*c4);
        float* dp = As + 4*c4*36 + r;
        dp[0]   = (v[qq].x - mu)*rstd*g.x + bb.x;
        dp[36]  = (v[qq].y - mu)*rstd*g.y + bb.y;
        dp[72]  = (v[qq].z - mu)*rstd*g.z + bb.z;
        dp[108] = (v[qq].w - mu)*rstd*g.w + bb.w;
      }
    }
    __syncthreads();
    const float* Wm = (y < 2) ? Wq : (y < 4) ? Wk : (y < 6) ? Wv : Wg;
    int cb = (y & 1) * 128;
    int rg = t >> 5, cg = t & 31;
    const float* bp = Wm + cb + 4*cg;
    const float* ap = As + 4*rg;
    float4 a0 = {0,0,0,0}, a1 = {0,0,0,0}, a2 = {0,0,0,0}, a3 = {0,0,0,0};
#pragma unroll 4
    for (int p = 0; p < 256; ++p) {
      float4 a  = *(const float4*)(ap + p*36);
      float4 bv = *(const float4*)(bp + p*256);
      a0.x = fmaf(a.x, bv.x, a0.x); a0.y = fmaf(a.x, bv.y, a0.y);
      a0.z = fmaf(a.x, bv.z, a0.z); a0.w = fmaf(a.x, bv.w, a0.w);
      a1.x = fmaf(a.y, bv.x, a1.x); a1.y = fmaf(a.y, bv.y, a1.y);
      a1.z = fmaf(a.y, bv.z, a1.z); a1.w = fmaf(a.y, bv.w, a1.w);
      a2.x = fmaf(a.z, bv.x, a2.x); a2.y = fmaf(a.z, bv.y, a2.y);
      a2.z = fmaf(a.z, bv.z, a2.z); a2.w = fmaf(a.z, bv.w, a2.w);
      a3.x = fmaf(a.w, bv.x, a3.x); a3.y = fmaf(a.w, bv.y, a3.y);
      a3.z = fmaf(a.w, bv.z, a3.z); a3.w = fmaf(a.w, bv.w, a3.w);
    }
    int mat = y >> 1;
    int col = cb + 4*cg;
    float* outp = (mat == 0) ? Qw : (mat == 1) ? Kw : (mat == 2) ? Vw : Gw;
    if (mat == 0) {
      const float qs = 0.17677669529663687f;
      a0.x*=qs; a0.y*=qs; a0.z*=qs; a0.w*=qs;
      a1.x*=qs; a1.y*=qs; a1.z*=qs; a1.w*=qs;
      a2.x*=qs; a2.y*=qs; a2.z*=qs; a2.w*=qs;
      a3.x*=qs; a3.y*=qs; a3.z*=qs; a3.w*=qs;
    }
    if (mat == 3) {
      float4 g4 = *(const float4*)(bg + col);
      a0.x = 1.f/(1.f+__expf(-(a0.x+g4.x))); a0.y = 1.f/(1.f+__expf(-(a0.y+g4.y)));
      a0.z = 1.f/(1.f+__expf(-(a0.z+g4.z))); a0.w = 1.f/(1.f+__expf(-(a0.w+g4.w)));
      a1.x = 1.f/(1.f+__expf(-(a1.x+g4.x))); a1.y = 1.f/(1.f+__expf(-(a1.y+g4.y)));
      a1.z = 1.f/(1.f+__expf(-(a1.z+g4.z))); a1.w = 1.f/(1.f+__expf(-(a1.w+g4.w)));
      a2.x = 1.f/(1.f+__expf(-(a2.x+g4.x))); a2.y = 1.f/(1.f+__expf(-(a2.y+g4.y)));
      a2.z = 1.f/(1.f+__expf(-(a2.z+g4.z))); a2.w = 1.f/(1.f+__expf(-(a2.w+g4.w)));
      a3.x = 1.f/(1.f+__expf(-(a3.x+g4.x))); a3.y = 1.f/(1.f+__expf(-(a3.y+g4.y)));
      a3.z = 1.f/(1.f+__expf(-(a3.z+g4.z))); a3.w = 1.f/(1.f+__expf(-(a3.w+g4.w)));
    }
    int orow = m0 + 4*rg;
    *(float4*)(outp + (size_t)(orow+0)*256 + col) = a0;
    *(float4*)(outp + (size_t)(orow+1)*256 + col) = a1;
    *(float4*)(outp + (size_t)(orow+2)*256 + col) = a2;
    *(float4*)(outp + (size_t)(orow+3)*256 + col) = a3;
    return;
  }

  // ---- pair bias path: one block per (b,i); wave handles 4 j-rows/iter ----
  int bb2 = blk - 512;
  int b = bb2 >> 9, i = bb2 & 511;
  int lane = t & 63, w = t >> 6;
  int grp = lane >> 4, f = lane & 15;

  // setup: W' = lpg*Wb for this lane's 8 k's (k = 4f..4f+3 and 64+4f..64+4f+3)
  float wb[64], wp[64];
  {
    const float* WbA = Wb + f*32;            // rows 4f..4f+3
    const float* WbB = Wb + (64 + 4*f)*8;    // rows 64+4f..
#pragma unroll
    for (int q = 0; q < 4; ++q) {
      float4 u0 = *(const float4*)(WbA + q*8);
      float4 u1 = *(const float4*)(WbA + q*8 + 4);
      wb[q*8+0]=u0.x; wb[q*8+1]=u0.y; wb[q*8+2]=u0.z; wb[q*8+3]=u0.w;
      wb[q*8+4]=u1.x; wb[q*8+5]=u1.y; wb[q*8+6]=u1.z; wb[q*8+7]=u1.w;
      float4 z0 = *(const float4*)(WbB + q*8);
      float4 z1 = *(const float4*)(WbB + q*8 + 4);
      wb[(4+q)*8+0]=z0.x; wb[(4+q)*8+1]=z0.y; wb[(4+q)*8+2]=z0.z; wb[(4+q)*8+3]=z0.w;
      wb[(4+q)*8+4]=z1.x; wb[(4+q)*8+5]=z1.y; wb[(4+q)*8+6]=z1.z; wb[(4+q)*8+7]=z1.w;
    }
  }
  float gl[8], bl[8];
  {
    float4 ga  = *(const float4*)(lpg + 4*f);
    float4 gb4 = *(const float4*)(lpg + 64 + 4*f);
    float4 ba  = *(const float4*)(lpb + 4*f);
    float4 bb4 = *(const float4*)(lpb + 64 + 4*f);
    gl[0]=ga.x; gl[1]=ga.y; gl[2]=ga.z; gl[3]=ga.w;
    gl[4]=gb4.x; gl[5]=gb4.y; gl[6]=gb4.z; gl[7]=gb4.w;
    bl[0]=ba.x; bl[1]=ba.y; bl[2]=ba.z; bl[3]=ba.w;
    bl[4]=bb4.x; bl[5]=bb4.y; bl[6]=bb4.z; bl[7]=bb4.w;
  }
  float cg[8] = {0,0,0,0,0,0,0,0}, cbv[8] = {0,0,0,0,0,0,0,0};
#pragma unroll
  for (int kk = 0; kk < 8; ++kk) {
#pragma unroll
    for (int n = 0; n < 8; ++n) {
      wp[kk*8+n] = gl[kk] * wb[kk*8+n];
      cg[n]  += wp[kk*8+n];
      cbv[n] = fmaf(bl[kk], wb[kk*8+n], cbv[n]);
    }
  }
#pragma unroll
  for (int mm = 1; mm < 16; mm <<= 1) {
#pragma unroll
    for (int n = 0; n < 8; ++n) {
      cg[n]  += __shfl_xor(cg[n],  mm);
      cbv[n] += __shfl_xor(cbv[n], mm);
    }
  }
  float cgsel, cbsel;
  SEL8(cg, f, cgsel);
  SEL8(cbv, f, cbsel);

  const float* prow0 = pair + (size_t)(b*512 + i) * (512*128);
  float* bw0 = biasw + (size_t)(b*8)*262144 + (size_t)i*512;
  for (int it = 0; it < 32; ++it) {
    int j = 16*it + 4*w + grp;
    const float* row = prow0 + (size_t)j*128;
    float4 x0 = *(const float4*)(row + 4*f);
    float4 x1 = *(const float4*)(row + 64 + 4*f);
    float xs[8] = {x0.x,x0.y,x0.z,x0.w, x1.x,x1.y,x1.z,x1.w};
    float s = 0.f, sq = 0.f;
    float dd[8] = {0,0,0,0,0,0,0,0};
#pragma unroll
    for (int kk = 0; kk < 8; ++kk) {
      s += xs[kk];
      sq = fmaf(xs[kk], xs[kk], sq);
#pragma unroll
      for (int n = 0; n < 8; ++n) dd[n] = fmaf(xs[kk], wp[kk*8+n], dd[n]);
    }
#pragma unroll
    for (int mm = 1; mm < 16; mm <<= 1) {
      s  += __shfl_xor(s,  mm);
      sq += __shfl_xor(sq, mm);
#pragma unroll
      for (int n = 0; n < 8; ++n) dd[n] += __shfl_xor(dd[n], mm);
    }
    float mu = s * (1.f/128.f);
    float var = fmaf(sq, 1.f/128.f, -mu*mu);
    float rstd = rsqrtf(var + 1e-5f);
    if (f < 8) {
      float dv;
      SEL8(dd, f, dv);
      bw0[(size_t)f*262144 + j] = fmaf(rstd, fmaf(-mu, cgsel, dv), cbsel);
    }
  }
}

// ---------------- K2: fused attention (online softmax, defer-rescale) ----------------
__global__ __launch_bounds__(256) void k_attn(
    const float* __restrict__ Qw, const float* __restrict__ Kw, const float* __restrict__ Vw,
    const float* __restrict__ Gw, const float* __restrict__ biasw, float* __restrict__ prew) {
  __shared__ __align__(16) float sm[18496];
  float* Kl = sm;
  float* Vl = sm + 9248;
  int t = threadIdx.x;
  int b = blockIdx.x >> 6;
  int i0 = (blockIdx.x & 63) << 3;
  int lane = t & 63, w = t >> 6;
  int i = lane >> 3, n = lane & 7;
  int qrow = b*512 + i0 + i;
  float4 q[8];
  const float* qp = Qw + (size_t)qrow*256 + n*32;
#pragma unroll
  for (int x = 0; x < 8; ++x) q[x] = *(const float4*)(qp + 4*x);
  const float* brow = biasw + (size_t)((b*8 + n)*512 + i0 + i)*512 + 8*w;
  float4 acc[8];
#pragma unroll
  for (int x = 0; x < 8; ++x) acc[x] = make_float4(0.f,0.f,0.f,0.f);
  float m = -1e30f, l = 0.f;
  int sr = t >> 3, sc = t & 7;
  const float* kbase = Kw + (size_t)(b*512 + sr)*256 + 4*sc;
  const float* vbase = Vw + (size_t)(b*512 + sr)*256 + 4*sc;
  float* kd = Kl + 36*sr + 4*sc;
  float* vd = Vl + 36*sr + 4*sc;
  for (int tt = 0; tt < 16; ++tt) {
    int j0 = tt*32;
    const float* ks = kbase + (size_t)j0*256;
    const float* vs = vbase + (size_t)j0*256;
#pragma unroll
    for (int s = 0; s < 8; ++s)
      *(float4*)(kd + 1156*s) = *(const float4*)(ks + 32*s);
#pragma unroll
    for (int s = 0; s < 8; ++s)
      *(float4*)(vd + 1156*s) = *(const float4*)(vs + 32*s);
    __syncthreads();
    float4 b0 = *(const float4*)(brow + j0);
    float4 b1 = *(const float4*)(brow + j0 + 4);
    float bb[8] = {b0.x,b0.y,b0.z,b0.w,b1.x,b1.y,b1.z,b1.w};
    float lg[8];
    const float* kp0 = Kl + 1156*n + 36*(8*w);
#pragma unroll
    for (int jj = 0; jj < 8; ++jj) {
      const float* kp = kp0 + 36*jj;
      float d0 = 0.f;
#pragma unroll
      for (int x = 0; x < 8; ++x) {
        float4 kk = *(const float4*)(kp + 4*x);
        d0 = fmaf(q[x].x, kk.x, d0);
        d0 = fmaf(q[x].y, kk.y, d0);
        d0 = fmaf(q[x].z, kk.z, d0);
        d0 = fmaf(q[x].w, kk.w, d0);
      }
      lg[jj] = d0 + bb[jj];
    }
    float tm = lg[0];
#pragma unroll
    for (int jj = 1; jj < 8; ++jj) tm = fmaxf(tm, lg[jj]);
    if (tm > m) {
      float nm = tm;
      float scl = __expf(m - nm);
      l *= scl;
#pragma unroll
      for (int x = 0; x < 8; ++x) {
        acc[x].x *= scl; acc[x].y *= scl; acc[x].z *= scl; acc[x].w *= scl;
      }
      m = nm;
    }
    const float* vp0 = Vl + 1156*n + 36*(8*w);
#pragma unroll
    for (int jj = 0; jj < 8; ++jj) {
      float p = __expf(lg[jj] - m);
      l += p;
      const float* vp = vp0 + 36*jj;
#pragma unroll
      for (int x = 0; x < 8; ++x) {
        float4 vv = *(const float4*)(vp + 4*x);
        acc[x].x = fmaf(p, vv.x, acc[x].x);
        acc[x].y = fmaf(p, vv.y, acc[x].y);
        acc[x].z = fmaf(p, vv.z, acc[x].z);
        acc[x].w = fmaf(p, vv.w, acc[x].w);
      }
    }
    __syncthreads();
  }
  // cross-wave merge
  float* me = sm + t*37;
  me[0] = m; me[1] = l;
#pragma unroll
  for (int x = 0; x < 8; ++x) {
    me[2+4*x+0] = acc[x].x; me[2+4*x+1] = acc[x].y;
    me[2+4*x+2] = acc[x].z; me[2+4*x+3] = acc[x].w;
  }
  __syncthreads();
  if (w == 0) {
    float mw[4], lw[4];
    float M = -1e30f;
#pragma unroll
    for (int v4 = 0; v4 < 4; ++v4) {
      const float* pe = sm + (v4*64 + lane)*37;
      mw[v4] = pe[0]; lw[v4] = pe[1];
      M = fmaxf(M, mw[v4]);
    }
    float Lsum = 0.f, ew[4];
#pragma unroll
    for (int v4 = 0; v4 < 4; ++v4) { ew[v4] = __expf(mw[v4] - M); Lsum = fmaf(lw[v4], ew[v4], Lsum); }
    float inv = 1.f / Lsum;
    float o[32];
#pragma unroll
    for (int h = 0; h < 32; ++h) o[h] = 0.f;
#pragma unroll
    for (int v4 = 0; v4 < 4; ++v4) {
      const float* pe = sm + (v4*64 + lane)*37 + 2;
      float e = ew[v4];
#pragma unroll
      for (int h = 0; h < 32; ++h) o[h] = fmaf(pe[h], e, o[h]);
    }
    const float* gp = Gw + (size_t)qrow*256 + n*32;
    float* op = prew + (size_t)qrow*256 + n*32;
#pragma unroll
    for (int x = 0; x < 8; ++x) {
      float4 g4 = *(const float4*)(gp + 4*x);
      float4 r;
      r.x = o[4*x+0]*inv*g4.x;
      r.y = o[4*x+1]*inv*g4.y;
      r.z = o[4*x+2]*inv*g4.z;
      r.w = o[4*x+3]*inv*g4.w;
      *(float4*)(op + 4*x) = r;
    }
  }
}

// ---------------- K3: output projection ----------------
__global__ __launch_bounds__(256) void k_out(
    const float* __restrict__ prew, const float* __restrict__ Wo, const float* __restrict__ bo,
    float* __restrict__ out) {
  __shared__ __align__(16) float As[256*36];
  int t = threadIdx.x;
  int m0 = blockIdx.x * 32;
  int y = blockIdx.y;
  {
    int r = t >> 3, c0 = t & 7;
    const float* srow = prew + (size_t)(m0 + r)*256;
#pragma unroll
    for (int qq = 0; qq < 8; ++qq) {
      int c4 = c0 + 8*qq;
      float4 v = *(const float4*)(srow + 4*c4);
      float* dp = As + 4*c4*36 + r;
      dp[0] = v.x; dp[36] = v.y; dp[72] = v.z; dp[108] = v.w;
    }
  }
  __syncthreads();
  int cb = y*128;
  int rg = t >> 5, cg = t & 31;
  int col = cb + 4*cg;
  const float* bp = Wo + col;
  const float* ap = As + 4*rg;
  float4 a0 = {0,0,0,0}, a1 = {0,0,0,0}, a2 = {0,0,0,0}, a3 = {0,0,0,0};
#pragma unroll 4
  for (int p = 0; p < 256; ++p) {
    float4 a  = *(const float4*)(ap + p*36);
    float4 bv = *(const float4*)(bp + p*256);
    a0.x = fmaf(a.x, bv.x, a0.x); a0.y = fmaf(a.x, bv.y, a0.y);
    a0.z = fmaf(a.x, bv.z, a0.z); a0.w = fmaf(a.x, bv.w, a0.w);
    a1.x = fmaf(a.y, bv.x, a1.x); a1.y = fmaf(a.y, bv.y, a1.y);
    a1.z = fmaf(a.y, bv.z, a1.z); a1.w = fmaf(a.y, bv.w, a1.w);
    a2.x = fmaf(a.z, bv.x, a2.x); a2.y = fmaf(a.z, bv.y, a2.y);
    a2.z = fmaf(a.z, bv.z, a2.z); a2.w = fmaf(a.z, bv.w, a2.w);
    a3.x = fmaf(a.w, bv.x, a3.x); a3.y = fmaf(a.w, bv.y, a3.y);
    a3.z = fmaf(a.w, bv.z, a3.z); a3.w = fmaf(a.w, bv.w, a3.w);
  }
  float4 b4 = *(const float4*)(bo + col);
  a0.x += b4.x; a0.y += b4.y; a0.z += b4.z; a0.w += b4.w;
  a1.x += b4.x; a1.y += b4.y; a1.z += b4.z; a1.w += b4.w;
  a2.x += b4.x; a2.y += b4.y; a2.z += b4.z; a2.w += b4.w;
  a3.x += b4.x; a3.y += b4.y; a3.z += b4.z; a3.w += b4.w;
  int orow = m0 + 4*rg;
  *(float4*)(out + (size_t)(orow+0)*256 + col) = a0;
  *(float4*)(out + (size_t)(orow+1)*256 + col) = a1;
  *(float4*)(out + (size_t)(orow+2)*256 + col) = a2;
  *(float4*)(out + (size_t)(orow+3)*256 + col) = a3;
}

extern "C" void kernel_launch(void* const* d_in, const int* in_sizes, int n_in,
                              void* d_out, int out_size, void* d_ws, size_t ws_size,
                              hipStream_t stream) {
  const float* seq  = (const float*)d_in[0];
  const float* pair = (const float*)d_in[1];
  const float* lsg  = (const float*)d_in[2];
  const float* lsb  = (const float*)d_in[3];
  const float* lpg  = (const float*)d_in[4];
  const float* lpb  = (const float*)d_in[5];
  const float* Wb   = (const float*)d_in[6];
  const float* Wq   = (const float*)d_in[7];
  const float* Wk   = (const float*)d_in[8];
  const float* Wv   = (const float*)d_in[9];
  const float* Wg   = (const float*)d_in[10];
  const float* bg   = (const float*)d_in[11];
  const float* Wo   = (const float*)d_in[12];
  const float* bo   = (const float*)d_in[13];
  float* ws   = (float*)d_ws;
  float* Qw   = ws + OFF_Q;
  float* Kw   = ws + OFF_K;
  float* Vw   = ws + OFF_V;
  float* Gw   = ws + OFF_G;
  float* prew = ws + OFF_PRE;
  float* biasw= ws + OFF_BIAS;
  float* out  = (float*)d_out;

  hipLaunchKernelGGL(k_mega, dim3(2560), dim3(256), 0, stream,
                     seq, lsg, lsb, lpg, lpb, Wb, Wq, Wk, Wv, Wg, bg, pair,
                     Qw, Kw, Vw, Gw, biasw);
  hipLaunchKernelGGL(k_attn, dim3(256), dim3(256), 0, stream,
                     Qw, Kw, Vw, Gw, biasw, prew);
  hipLaunchKernelGGL(k_out, dim3(64, 2), dim3(256), 0, stream,
                     prew, Wo, bo, out);
}

// Round 3
// 242.467 us; speedup vs baseline: 1.1312x; 1.0357x over previous
//
#include <hip/hip_runtime.h>
#include <math.h>

// ws offsets (floats)
#define OFF_Q    0
#define OFF_K    (524288)
#define OFF_V    (524288*2)
#define OFF_G    (524288*3)
#define OFF_PRE  (524288*4)
#define OFF_BIAS (524288*5)

// ---------- DPP helpers (16-lane row reduce, zero DS traffic) ----------
template <int CTRL>
__device__ __forceinline__ float dpp_mov(float x) {
  return __int_as_float(__builtin_amdgcn_update_dpp(0, __float_as_int(x), CTRL, 0xF, 0xF, true));
}
template <int CTRL>
__device__ __forceinline__ float dpp_add(float x) { return x + dpp_mov<CTRL>(x); }
// full sum across each 16-lane group: xor1, xor2, xor7(half-mirror), xor15(mirror)
__device__ __forceinline__ float red16(float v) {
  v = dpp_add<0xB1>(v);    // quad_perm [1,0,3,2]  (xor 1)
  v = dpp_add<0x4E>(v);    // quad_perm [2,3,0,1]  (xor 2)
  v = dpp_add<0x141>(v);   // row_half_mirror      (xor 7)
  v = dpp_add<0x140>(v);   // row_mirror           (xor 15)
  return v;
}

// select a[f] from 8 register-resident floats (constant indices only)
#define SEL8(a, f, out) do { \
  float _s0 = ((f)&1) ? a[1] : a[0]; \
  float _s1 = ((f)&1) ? a[3] : a[2]; \
  float _s2 = ((f)&1) ? a[5] : a[4]; \
  float _s3 = ((f)&1) ? a[7] : a[6]; \
  float _t0 = ((f)&2) ? _s1 : _s0; \
  float _t1 = ((f)&2) ? _s3 : _s2; \
  out = ((f)&4) ? _t1 : _t0; \
} while(0)

__device__ __forceinline__ float4 sel8_f4(const float4* a, int f) {
  float4 s0 = (f&1) ? a[1] : a[0];
  float4 s1 = (f&1) ? a[3] : a[2];
  float4 s2 = (f&1) ? a[5] : a[4];
  float4 s3 = (f&1) ? a[7] : a[6];
  float4 t0 = (f&2) ? s1 : s0;
  float4 t1 = (f&2) ? s3 : s2;
  return (f&4) ? t1 : t0;
}

__device__ __forceinline__ float dot4(float4 a, float4 b, float acc) {
  acc = fmaf(a.x, b.x, acc); acc = fmaf(a.y, b.y, acc);
  acc = fmaf(a.z, b.z, acc); return fmaf(a.w, b.w, acc);
}

// online-softmax merge level within 8-lane group (lane ^= CTRL pattern)
template <int CTRL>
__device__ __forceinline__ void merge_dpp(float& m, float& l, float4* acc) {
  float m2 = dpp_mov<CTRL>(m);
  float l2 = dpp_mov<CTRL>(l);
  float M = fmaxf(m, m2);
  float ea = __expf(m - M), eb = __expf(m2 - M);
  l = l*ea + l2*eb;
#pragma unroll
  for (int x = 0; x < 8; ++x) {
    acc[x].x = acc[x].x*ea + dpp_mov<CTRL>(acc[x].x)*eb;
    acc[x].y = acc[x].y*ea + dpp_mov<CTRL>(acc[x].y)*eb;
    acc[x].z = acc[x].z*ea + dpp_mov<CTRL>(acc[x].z)*eb;
    acc[x].w = acc[x].w*ea + dpp_mov<CTRL>(acc[x].w)*eb;
  }
  m = M;
}

// ---------------- K1: mega (qkvg with fused LN  +  pair LN/bias) ----------------
__global__ __launch_bounds__(256, 3) void k_mega(
    const float* __restrict__ seq, const float* __restrict__ lsg, const float* __restrict__ lsb,
    const float* __restrict__ lpg, const float* __restrict__ lpb, const float* __restrict__ Wb,
    const float* __restrict__ Wq, const float* __restrict__ Wk, const float* __restrict__ Wv,
    const float* __restrict__ Wg, const float* __restrict__ bg, const float* __restrict__ pair,
    float* __restrict__ Qw, float* __restrict__ Kw, float* __restrict__ Vw, float* __restrict__ Gw,
    float* __restrict__ biasw) {
  __shared__ __align__(16) float As[256*36];
  int t = threadIdx.x;
  int blk = blockIdx.x;

  if (blk < 512) {
    // ---- qkvg path: LN(seq rows) + GEMM 32x(256)x128-slice ----
    int m0 = (blk >> 3) * 32;
    int y = blk & 7;
    {
      int r = t >> 3, c0 = t & 7;
      const float* srow = seq + (size_t)(m0 + r) * 256;
      float4 v[8];
      float s = 0.f, sq = 0.f;
#pragma unroll
      for (int qq = 0; qq < 8; ++qq) {
        v[qq] = *(const float4*)(srow + 4*(c0 + 8*qq));
        s += v[qq].x + v[qq].y + v[qq].z + v[qq].w;
        sq = fmaf(v[qq].x, v[qq].x, sq); sq = fmaf(v[qq].y, v[qq].y, sq);
        sq = fmaf(v[qq].z, v[qq].z, sq); sq = fmaf(v[qq].w, v[qq].w, sq);
      }
#pragma unroll
      for (int mm = 1; mm < 8; mm <<= 1) { s += __shfl_xor(s, mm); sq += __shfl_xor(sq, mm); }
      float mu = s * (1.f/256.f);
      float var = sq * (1.f/256.f) - mu*mu;
      float rstd = rsqrtf(var + 1e-5f);
#pragma unroll
      for (int qq = 0; qq < 8; ++qq) {
        int c4 = c0 + 8*qq;
        float4 g  = *(const float4*)(lsg + 4*c4);
        float4 bb = *(const float4*)(lsb + 4*c4);
        float* dp = As + 4*c4*36 + r;
        dp[0]   = (v[qq].x - mu)*rstd*g.x + bb.x;
        dp[36]  = (v[qq].y - mu)*rstd*g.y + bb.y;
        dp[72]  = (v[qq].z - mu)*rstd*g.z + bb.z;
        dp[108] = (v[qq].w - mu)*rstd*g.w + bb.w;
      }
    }
    __syncthreads();
    const float* Wm = (y < 2) ? Wq : (y < 4) ? Wk : (y < 6) ? Wv : Wg;
    int cb = (y & 1) * 128;
    int rg = t >> 5, cg2 = t & 31;
    const float* bp = Wm + cb + 4*cg2;
    const float* ap = As + 4*rg;
    float4 a0 = {0,0,0,0}, a1 = {0,0,0,0}, a2 = {0,0,0,0}, a3 = {0,0,0,0};
#pragma unroll 4
    for (int p = 0; p < 256; ++p) {
      float4 a  = *(const float4*)(ap + p*36);
      float4 bv = *(const float4*)(bp + p*256);
      a0.x = fmaf(a.x, bv.x, a0.x); a0.y = fmaf(a.x, bv.y, a0.y);
      a0.z = fmaf(a.x, bv.z, a0.z); a0.w = fmaf(a.x, bv.w, a0.w);
      a1.x = fmaf(a.y, bv.x, a1.x); a1.y = fmaf(a.y, bv.y, a1.y);
      a1.z = fmaf(a.y, bv.z, a1.z); a1.w = fmaf(a.y, bv.w, a1.w);
      a2.x = fmaf(a.z, bv.x, a2.x); a2.y = fmaf(a.z, bv.y, a2.y);
      a2.z = fmaf(a.z, bv.z, a2.z); a2.w = fmaf(a.z, bv.w, a2.w);
      a3.x = fmaf(a.w, bv.x, a3.x); a3.y = fmaf(a.w, bv.y, a3.y);
      a3.z = fmaf(a.w, bv.z, a3.z); a3.w = fmaf(a.w, bv.w, a3.w);
    }
    int mat = y >> 1;
    int col = cb + 4*cg2;
    float* outp = (mat == 0) ? Qw : (mat == 1) ? Kw : (mat == 2) ? Vw : Gw;
    if (mat == 0) {
      const float qs = 0.17677669529663687f;
      a0.x*=qs; a0.y*=qs; a0.z*=qs; a0.w*=qs;
      a1.x*=qs; a1.y*=qs; a1.z*=qs; a1.w*=qs;
      a2.x*=qs; a2.y*=qs; a2.z*=qs; a2.w*=qs;
      a3.x*=qs; a3.y*=qs; a3.z*=qs; a3.w*=qs;
    }
    if (mat == 3) {
      float4 g4 = *(const float4*)(bg + col);
      a0.x = 1.f/(1.f+__expf(-(a0.x+g4.x))); a0.y = 1.f/(1.f+__expf(-(a0.y+g4.y)));
      a0.z = 1.f/(1.f+__expf(-(a0.z+g4.z))); a0.w = 1.f/(1.f+__expf(-(a0.w+g4.w)));
      a1.x = 1.f/(1.f+__expf(-(a1.x+g4.x))); a1.y = 1.f/(1.f+__expf(-(a1.y+g4.y)));
      a1.z = 1.f/(1.f+__expf(-(a1.z+g4.z))); a1.w = 1.f/(1.f+__expf(-(a1.w+g4.w)));
      a2.x = 1.f/(1.f+__expf(-(a2.x+g4.x))); a2.y = 1.f/(1.f+__expf(-(a2.y+g4.y)));
      a2.z = 1.f/(1.f+__expf(-(a2.z+g4.z))); a2.w = 1.f/(1.f+__expf(-(a2.w+g4.w)));
      a3.x = 1.f/(1.f+__expf(-(a3.x+g4.x))); a3.y = 1.f/(1.f+__expf(-(a3.y+g4.y)));
      a3.z = 1.f/(1.f+__expf(-(a3.z+g4.z))); a3.w = 1.f/(1.f+__expf(-(a3.w+g4.w)));
    }
    int orow = m0 + 4*rg;
    *(float4*)(outp + (size_t)(orow+0)*256 + col) = a0;
    *(float4*)(outp + (size_t)(orow+1)*256 + col) = a1;
    *(float4*)(outp + (size_t)(orow+2)*256 + col) = a2;
    *(float4*)(outp + (size_t)(orow+3)*256 + col) = a3;
    return;
  }

  // ---- pair bias path: one block per (b,i); DPP reduce (no LDS, no ds_swizzle) ----
  int bb2 = blk - 512;
  int b = bb2 >> 9, i = bb2 & 511;
  int lane = t & 63, w = t >> 6;
  int grp = lane >> 4, f = lane & 15;

  // lane's 8 k's: {4f..4f+3} and {64+4f..64+4f+3}; wp = gamma*Wb, cg/cb partials
  float wp[64];
  float cg[8] = {0,0,0,0,0,0,0,0}, cbv[8] = {0,0,0,0,0,0,0,0};
#pragma unroll
  for (int q = 0; q < 4; ++q) {
    int kA = 4*f + q, kB = 64 + 4*f + q;
    float gA = lpg[kA], bA = lpb[kA];
    float gB = lpg[kB], bB = lpb[kB];
    float4 uA0 = *(const float4*)(Wb + kA*8);
    float4 uA1 = *(const float4*)(Wb + kA*8 + 4);
    float4 uB0 = *(const float4*)(Wb + kB*8);
    float4 uB1 = *(const float4*)(Wb + kB*8 + 4);
    wp[q*8+0] = gA*uA0.x; cg[0] += wp[q*8+0]; cbv[0] = fmaf(bA, uA0.x, cbv[0]);
    wp[q*8+1] = gA*uA0.y; cg[1] += wp[q*8+1]; cbv[1] = fmaf(bA, uA0.y, cbv[1]);
    wp[q*8+2] = gA*uA0.z; cg[2] += wp[q*8+2]; cbv[2] = fmaf(bA, uA0.z, cbv[2]);
    wp[q*8+3] = gA*uA0.w; cg[3] += wp[q*8+3]; cbv[3] = fmaf(bA, uA0.w, cbv[3]);
    wp[q*8+4] = gA*uA1.x; cg[4] += wp[q*8+4]; cbv[4] = fmaf(bA, uA1.x, cbv[4]);
    wp[q*8+5] = gA*uA1.y; cg[5] += wp[q*8+5]; cbv[5] = fmaf(bA, uA1.y, cbv[5]);
    wp[q*8+6] = gA*uA1.z; cg[6] += wp[q*8+6]; cbv[6] = fmaf(bA, uA1.z, cbv[6]);
    wp[q*8+7] = gA*uA1.w; cg[7] += wp[q*8+7]; cbv[7] = fmaf(bA, uA1.w, cbv[7]);
    int qb8 = (4+q)*8;
    wp[qb8+0] = gB*uB0.x; cg[0] += wp[qb8+0]; cbv[0] = fmaf(bB, uB0.x, cbv[0]);
    wp[qb8+1] = gB*uB0.y; cg[1] += wp[qb8+1]; cbv[1] = fmaf(bB, uB0.y, cbv[1]);
    wp[qb8+2] = gB*uB0.z; cg[2] += wp[qb8+2]; cbv[2] = fmaf(bB, uB0.z, cbv[2]);
    wp[qb8+3] = gB*uB0.w; cg[3] += wp[qb8+3]; cbv[3] = fmaf(bB, uB0.w, cbv[3]);
    wp[qb8+4] = gB*uB1.x; cg[4] += wp[qb8+4]; cbv[4] = fmaf(bB, uB1.x, cbv[4]);
    wp[qb8+5] = gB*uB1.y; cg[5] += wp[qb8+5]; cbv[5] = fmaf(bB, uB1.y, cbv[5]);
    wp[qb8+6] = gB*uB1.z; cg[6] += wp[qb8+6]; cbv[6] = fmaf(bB, uB1.z, cbv[6]);
    wp[qb8+7] = gB*uB1.w; cg[7] += wp[qb8+7]; cbv[7] = fmaf(bB, uB1.w, cbv[7]);
  }
#pragma unroll
  for (int n2 = 0; n2 < 8; ++n2) { cg[n2] = red16(cg[n2]); cbv[n2] = red16(cbv[n2]); }
  float cgsel, cbsel;
  SEL8(cg, f, cgsel);
  SEL8(cbv, f, cbsel);

  const float* prow0 = pair + (size_t)(b*512 + i) * (512*128);
  float* bw0 = biasw + (size_t)(b*8)*262144 + (size_t)i*512;

  int j = 4*w + grp;
  const float* rp = prow0 + (size_t)j*128 + 4*f;
  float4 x0 = *(const float4*)rp;
  float4 x1 = *(const float4*)(rp + 64);
#pragma unroll 2
  for (int it = 0; it < 32; ++it) {
    float4 y0, y1;
    if (it < 31) {
      const float* rn = rp + 16*128;
      y0 = *(const float4*)rn;
      y1 = *(const float4*)(rn + 64);
    }
    float s  = x0.x + x0.y + x0.z + x0.w + x1.x + x1.y + x1.z + x1.w;
    float sq = x0.x*x0.x;
    sq = fmaf(x0.y, x0.y, sq); sq = fmaf(x0.z, x0.z, sq); sq = fmaf(x0.w, x0.w, sq);
    sq = fmaf(x1.x, x1.x, sq); sq = fmaf(x1.y, x1.y, sq);
    sq = fmaf(x1.z, x1.z, sq); sq = fmaf(x1.w, x1.w, sq);
    float dd[8];
#pragma unroll
    for (int n2 = 0; n2 < 8; ++n2) {
      float d = x0.x * wp[n2];
      d = fmaf(x0.y, wp[8+n2],  d);
      d = fmaf(x0.z, wp[16+n2], d);
      d = fmaf(x0.w, wp[24+n2], d);
      d = fmaf(x1.x, wp[32+n2], d);
      d = fmaf(x1.y, wp[40+n2], d);
      d = fmaf(x1.z, wp[48+n2], d);
      d = fmaf(x1.w, wp[56+n2], d);
      dd[n2] = d;
    }
    s  = red16(s);
    sq = red16(sq);
#pragma unroll
    for (int n2 = 0; n2 < 8; ++n2) dd[n2] = red16(dd[n2]);
    float mu = s * (1.f/128.f);
    float var = fmaf(sq, 1.f/128.f, -mu*mu);
    float rstd = rsqrtf(var + 1e-5f);
    if (f < 8) {
      float dv;
      SEL8(dd, f, dv);
      bw0[(size_t)f*262144 + j] = fmaf(rstd, fmaf(-mu, cgsel, dv), cbsel);
    }
    j += 16; rp += 16*128;
    x0 = y0; x1 = y1;
  }
}

// ---------------- K2: fused attention, 8 waves, 2 q-rows/lane ----------------
#define KVS 260   // LDS row stride (floats) for K/V tiles
#define BBS 36    // LDS row stride for bias tile rows (il*8+n major)

__global__ __launch_bounds__(512, 2) void k_attn2(
    const float* __restrict__ Qw, const float* __restrict__ Kw, const float* __restrict__ Vw,
    const float* __restrict__ Gw, const float* __restrict__ biasw, float* __restrict__ prew) {
  __shared__ __align__(16) float Kb[2][32*KVS];
  __shared__ __align__(16) float Vb[2][32*KVS];
  __shared__ __align__(16) float Bb[2][64*BBS];
  __shared__ __align__(16) float scr[4*8*68];

  int t = threadIdx.x, lane = t & 63, w = t >> 6;
  int b = blockIdx.x >> 6, i0 = (blockIdx.x & 63) << 3;
  int n = lane >> 3, js = lane & 7;
  int ip = w & 3, jset = w >> 2;
  int ila = 2*ip, ilb = ila + 1;
  size_t qra = (size_t)(b*512 + i0 + ila);
  size_t qrb = qra + 1;

  float4 qa[8], qb[8];
  {
    const float* pa = Qw + qra*256 + n*32;
    const float* pb = Qw + qrb*256 + n*32;
#pragma unroll
    for (int x = 0; x < 8; ++x) { qa[x] = *(const float4*)(pa + 4*x); qb[x] = *(const float4*)(pb + 4*x); }
  }
  float4 acca[8], accb[8];
#pragma unroll
  for (int x = 0; x < 8; ++x) { acca[x] = make_float4(0,0,0,0); accb[x] = make_float4(0,0,0,0); }
  float ma = -1e30f, la = 0.f, mb2 = -1e30f, lb2 = 0.f;

  const float* Kg = Kw + (size_t)(b*512)*256;
  const float* Vg = Vw + (size_t)(b*512)*256;
  // bias staging ids: idx = il*8 + n_  (il major for bank spread)
  int sidx = 8*w + (lane >> 3);           // 8 rows per wave
  int s_il = sidx >> 3, s_n = sidx & 7;
  const float* bgsrc = biasw + (size_t)((b*8 + s_n)*512 + i0 + s_il)*512 + 4*(lane & 7);

  float4 sk[4], sv[4], sb;

#define STAGE_LOAD(tn) { \
    const float* ks_ = Kg + (size_t)((tn)*32 + 4*w)*256 + 4*lane; \
    const float* vs_ = Vg + (size_t)((tn)*32 + 4*w)*256 + 4*lane; \
    sk[0] = *(const float4*)(ks_);        sk[1] = *(const float4*)(ks_ + 256); \
    sk[2] = *(const float4*)(ks_ + 512);  sk[3] = *(const float4*)(ks_ + 768); \
    sv[0] = *(const float4*)(vs_);        sv[1] = *(const float4*)(vs_ + 256); \
    sv[2] = *(const float4*)(vs_ + 512);  sv[3] = *(const float4*)(vs_ + 768); \
    sb = *(const float4*)(bgsrc + (tn)*32); \
  }
#define STAGE_WRITE(tn) { int bf_ = (tn) & 1; \
    float* kd_ = &Kb[bf_][(4*w)*KVS + 4*lane]; \
    *(float4*)(kd_)         = sk[0]; *(float4*)(kd_ + KVS)   = sk[1]; \
    *(float4*)(kd_ + 2*KVS) = sk[2]; *(float4*)(kd_ + 3*KVS) = sk[3]; \
    float* vd_ = &Vb[bf_][(4*w)*KVS + 4*lane]; \
    *(float4*)(vd_)         = sv[0]; *(float4*)(vd_ + KVS)   = sv[1]; \
    *(float4*)(vd_ + 2*KVS) = sv[2]; *(float4*)(vd_ + 3*KVS) = sv[3]; \
    *(float4*)(&Bb[bf_][sidx*BBS + 4*(lane & 7)]) = sb; \
  }

  STAGE_LOAD(0);
  STAGE_WRITE(0);
  __syncthreads();

  int jl0 = jset*16 + js;
  for (int tt = 0; tt < 16; ++tt) {
    int cur = tt & 1;
    if (tt < 15) STAGE_LOAD(tt+1);

    const float* Kt = Kb[cur];
    const float* Vt = Vb[cur];
    const float* Bt = Bb[cur];

    float lga0, lga1, lgb0, lgb1;
    {
      const float* kp = Kt + jl0*KVS + n*32;
      float da = 0.f, db = 0.f;
#pragma unroll
      for (int x = 0; x < 8; ++x) {
        float4 kk = *(const float4*)(kp + 4*x);
        da = dot4(qa[x], kk, da); db = dot4(qb[x], kk, db);
      }
      lga0 = da + Bt[(ila*8 + n)*BBS + jl0];
      lgb0 = db + Bt[(ilb*8 + n)*BBS + jl0];
    }
    {
      const float* kp = Kt + (jl0+8)*KVS + n*32;
      float da = 0.f, db = 0.f;
#pragma unroll
      for (int x = 0; x < 8; ++x) {
        float4 kk = *(const float4*)(kp + 4*x);
        da = dot4(qa[x], kk, da); db = dot4(qb[x], kk, db);
      }
      lga1 = da + Bt[(ila*8 + n)*BBS + jl0 + 8];
      lgb1 = db + Bt[(ilb*8 + n)*BBS + jl0 + 8];
    }
    // online softmax row a
    {
      float tm = fmaxf(lga0, lga1);
      float M = fmaxf(ma, tm);
      float sc = __expf(ma - M);
      la *= sc;
#pragma unroll
      for (int x = 0; x < 8; ++x) {
        acca[x].x *= sc; acca[x].y *= sc; acca[x].z *= sc; acca[x].w *= sc;
      }
      ma = M;
    }
    // online softmax row b
    {
      float tm = fmaxf(lgb0, lgb1);
      float M = fmaxf(mb2, tm);
      float sc = __expf(mb2 - M);
      lb2 *= sc;
#pragma unroll
      for (int x = 0; x < 8; ++x) {
        accb[x].x *= sc; accb[x].y *= sc; accb[x].z *= sc; accb[x].w *= sc;
      }
      mb2 = M;
    }
    float pa0 = __expf(lga0 - ma), pa1 = __expf(lga1 - ma);
    float pb0 = __expf(lgb0 - mb2), pb1 = __expf(lgb1 - mb2);
    la += pa0 + pa1; lb2 += pb0 + pb1;
    {
      const float* vp = Vt + jl0*KVS + n*32;
#pragma unroll
      for (int x = 0; x < 8; ++x) {
        float4 vv = *(const float4*)(vp + 4*x);
        acca[x].x = fmaf(pa0, vv.x, acca[x].x); acca[x].y = fmaf(pa0, vv.y, acca[x].y);
        acca[x].z = fmaf(pa0, vv.z, acca[x].z); acca[x].w = fmaf(pa0, vv.w, acca[x].w);
        accb[x].x = fmaf(pb0, vv.x, accb[x].x); accb[x].y = fmaf(pb0, vv.y, accb[x].y);
        accb[x].z = fmaf(pb0, vv.z, accb[x].z); accb[x].w = fmaf(pb0, vv.w, accb[x].w);
      }
    }
    {
      const float* vp = Vt + (jl0+8)*KVS + n*32;
#pragma unroll
      for (int x = 0; x < 8; ++x) {
        float4 vv = *(const float4*)(vp + 4*x);
        acca[x].x = fmaf(pa1, vv.x, acca[x].x); acca[x].y = fmaf(pa1, vv.y, acca[x].y);
        acca[x].z = fmaf(pa1, vv.z, acca[x].z); acca[x].w = fmaf(pa1, vv.w, acca[x].w);
        accb[x].x = fmaf(pb1, vv.x, accb[x].x); accb[x].y = fmaf(pb1, vv.y, accb[x].y);
        accb[x].z = fmaf(pb1, vv.z, accb[x].z); accb[x].w = fmaf(pb1, vv.w, accb[x].w);
      }
    }

    if (tt < 15) STAGE_WRITE(tt+1);
    __syncthreads();
  }

  // ---- merge: 8-lane (js) butterfly via DPP, then cross-jset via LDS ----
  merge_dpp<0xB1>(ma, la, acca);   merge_dpp<0xB1>(mb2, lb2, accb);
  merge_dpp<0x4E>(ma, la, acca);   merge_dpp<0x4E>(mb2, lb2, accb);
  merge_dpp<0x141>(ma, la, acca);  merge_dpp<0x141>(mb2, lb2, accb);

  float4 fa = sel8_f4(acca, js);
  float4 fb = sel8_f4(accb, js);

  if (jset == 1) {
    int base = (ip*8 + n)*68;
    *(float4*)(scr + base + 4*js) = fa;
    *(float4*)(scr + base + 32 + 4*js) = fb;
    if (js == 0) { scr[base+64] = ma; scr[base+65] = la; scr[base+66] = mb2; scr[base+67] = lb2; }
  }
  __syncthreads();
  if (jset == 0) {
    int base = (ip*8 + n)*68;
    float4 a2 = *(const float4*)(scr + base + 4*js);
    float4 b2 = *(const float4*)(scr + base + 32 + 4*js);
    float m2a = scr[base+64], l2a = scr[base+65];
    float m2b = scr[base+66], l2b = scr[base+67];
    // row a
    {
      float M = fmaxf(ma, m2a);
      float ea = __expf(ma - M), eb = __expf(m2a - M);
      float inv = 1.f / (la*ea + l2a*eb);
      float4 g4 = *(const float4*)(Gw + qra*256 + n*32 + 4*js);
      float4 r;
      r.x = (fa.x*ea + a2.x*eb) * inv * g4.x;
      r.y = (fa.y*ea + a2.y*eb) * inv * g4.y;
      r.z = (fa.z*ea + a2.z*eb) * inv * g4.z;
      r.w = (fa.w*ea + a2.w*eb) * inv * g4.w;
      *(float4*)(prew + qra*256 + n*32 + 4*js) = r;
    }
    // row b
    {
      float M = fmaxf(mb2, m2b);
      float ea = __expf(mb2 - M), eb = __expf(m2b - M);
      float inv = 1.f / (lb2*ea + l2b*eb);
      float4 g4 = *(const float4*)(Gw + qrb*256 + n*32 + 4*js);
      float4 r;
      r.x = (fb.x*ea + b2.x*eb) * inv * g4.x;
      r.y = (fb.y*ea + b2.y*eb) * inv * g4.y;
      r.z = (fb.z*ea + b2.z*eb) * inv * g4.z;
      r.w = (fb.w*ea + b2.w*eb) * inv * g4.w;
      *(float4*)(prew + qrb*256 + n*32 + 4*js) = r;
    }
  }
}

// ---------------- K3: output projection ----------------
__global__ __launch_bounds__(256) void k_out(
    const float* __restrict__ prew, const float* __restrict__ Wo, const float* __restrict__ bo,
    float* __restrict__ out) {
  __shared__ __align__(16) float As[256*36];
  int t = threadIdx.x;
  int m0 = blockIdx.x * 32;
  int y = blockIdx.y;
  {
    int r = t >> 3, c0 = t & 7;
    const float* srow = prew + (size_t)(m0 + r)*256;
#pragma unroll
    for (int qq = 0; qq < 8; ++qq) {
      int c4 = c0 + 8*qq;
      float4 v = *(const float4*)(srow + 4*c4);
      float* dp = As + 4*c4*36 + r;
      dp[0] = v.x; dp[36] = v.y; dp[72] = v.z; dp[108] = v.w;
    }
  }
  __syncthreads();
  int cb = y*128;
  int rg = t >> 5, cg2 = t & 31;
  int col = cb + 4*cg2;
  const float* bp = Wo + col;
  const float* ap = As + 4*rg;
  float4 a0 = {0,0,0,0}, a1 = {0,0,0,0}, a2 = {0,0,0,0}, a3 = {0,0,0,0};
#pragma unroll 4
  for (int p = 0; p < 256; ++p) {
    float4 a  = *(const float4*)(ap + p*36);
    float4 bv = *(const float4*)(bp + p*256);
    a0.x = fmaf(a.x, bv.x, a0.x); a0.y = fmaf(a.x, bv.y, a0.y);
    a0.z = fmaf(a.x, bv.z, a0.z); a0.w = fmaf(a.x, bv.w, a0.w);
    a1.x = fmaf(a.y, bv.x, a1.x); a1.y = fmaf(a.y, bv.y, a1.y);
    a1.z = fmaf(a.y, bv.z, a1.z); a1.w = fmaf(a.y, bv.w, a1.w);
    a2.x = fmaf(a.z, bv.x, a2.x); a2.y = fmaf(a.z, bv.y, a2.y);
    a2.z = fmaf(a.z, bv.z, a2.z); a2.w = fmaf(a.z, bv.w, a2.w);
    a3.x = fmaf(a.w, bv.x, a3.x); a3.y = fmaf(a.w, bv.y, a3.y);
    a3.z = fmaf(a.w, bv.z, a3.z); a3.w = fmaf(a.w, bv.w, a3.w);
  }
  float4 b4 = *(const float4*)(bo + col);
  a0.x += b4.x; a0.y += b4.y; a0.z += b4.z; a0.w += b4.w;
  a1.x += b4.x; a1.y += b4.y; a1.z += b4.z; a1.w += b4.w;
  a2.x += b4.x; a2.y += b4.y; a2.z += b4.z; a2.w += b4.w;
  a3.x += b4.x; a3.y += b4.y; a3.z += b4.z; a3.w += b4.w;
  int orow = m0 + 4*rg;
  *(float4*)(out + (size_t)(orow+0)*256 + col) = a0;
  *(float4*)(out + (size_t)(orow+1)*256 + col) = a1;
  *(float4*)(out + (size_t)(orow+2)*256 + col) = a2;
  *(float4*)(out + (size_t)(orow+3)*256 + col) = a3;
}

extern "C" void kernel_launch(void* const* d_in, const int* in_sizes, int n_in,
                              void* d_out, int out_size, void* d_ws, size_t ws_size,
                              hipStream_t stream) {
  const float* seq  = (const float*)d_in[0];
  const float* pair = (const float*)d_in[1];
  const float* lsg  = (const float*)d_in[2];
  const float* lsb  = (const float*)d_in[3];
  const float* lpg  = (const float*)d_in[4];
  const float* lpb  = (const float*)d_in[5];
  const float* Wb   = (const float*)d_in[6];
  const float* Wq   = (const float*)d_in[7];
  const float* Wk   = (const float*)d_in[8];
  const float* Wv   = (const float*)d_in[9];
  const float* Wg   = (const float*)d_in[10];
  const float* bg   = (const float*)d_in[11];
  const float* Wo   = (const float*)d_in[12];
  const float* bo   = (const float*)d_in[13];
  float* ws   = (float*)d_ws;
  float* Qw   = ws + OFF_Q;
  float* Kw   = ws + OFF_K;
  float* Vw   = ws + OFF_V;
  float* Gw   = ws + OFF_G;
  float* prew = ws + OFF_PRE;
  float* biasw= ws + OFF_BIAS;
  float* out  = (float*)d_out;

  hipLaunchKernelGGL(k_mega, dim3(2560), dim3(256), 0, stream,
                     seq, lsg, lsb, lpg, lpb, Wb, Wq, Wk, Wv, Wg, bg, pair,
                     Qw, Kw, Vw, Gw, biasw);
  hipLaunchKernelGGL(k_attn2, dim3(256), dim3(512), 0, stream,
                     Qw, Kw, Vw, Gw, biasw, prew);
  hipLaunchKernelGGL(k_out, dim3(64, 2), dim3(256), 0, stream,
                     prew, Wo, bo, out);
}